// Round 2
// baseline (1379.855 us; speedup 1.0000x reference)
//
#include <hip/hip_runtime.h>
#include <math.h>

#define B_ 4
#define T_ 4096
#define D_ 1024
#define H_ 16
#define DH_ 64
#define M_ (B_*T_)      // 16384
#define HD_ (H_*DH_)    // 1024
#define NC_ 64          // number of chunks along T
#define CS_ 64          // chunk size (NC_*CS_ == T_)
#define PI_4 0.78539816339744830962f
#define EPS_ 1e-6f

// ---------------- K0: transpose W_O [D,Dh,H] -> Wo2 [H*Dh, D] ----------------
__global__ __launch_bounds__(256) void transpose_wo(const float* __restrict__ WO,
                                                    float* __restrict__ Wo2) {
    int f = blockIdx.x * 256 + threadIdx.x;          // over D_*HD_ = 1M elems
    int d = f >> 10;
    int rem = f & 1023;
    int e = rem >> 4;
    int h = rem & 15;
    Wo2[(size_t)(h * DH_ + e) * D_ + d] = WO[f];
}

// ---------------- K1: q/k projections + tanh + cos/sin ----------------
// outputs cq,sq,ck,sk each laid out [B,H,T]
__global__ __launch_bounds__(256) void qk_proj(const float* __restrict__ q,
                                               const float* __restrict__ wq,
                                               const float* __restrict__ wk,
                                               float* __restrict__ cq, float* __restrict__ sq,
                                               float* __restrict__ ck, float* __restrict__ sk) {
    __shared__ float row[D_];
    int m = blockIdx.x;
    int tid = threadIdx.x;
    const float4* src = (const float4*)(q + (size_t)m * D_);
    ((float4*)row)[tid] = src[tid];
    __syncthreads();
    int out = tid >> 3;          // 0..31
    int sub = tid & 7;
    int h = out >> 1;
    int isK = out & 1;
    const float* w = (isK ? wk : wq) + (size_t)h * D_;
    float acc = 0.f;
#pragma unroll 8
    for (int i = 0; i < 128; ++i) {
        int d = sub + (i << 3);
        acc = fmaf(row[d], w[d], acc);
    }
    acc += __shfl_xor(acc, 1);
    acc += __shfl_xor(acc, 2);
    acc += __shfl_xor(acc, 4);
    if (sub == 0) {
        float v = tanhf(acc) * PI_4;
        int b = m >> 12, t = m & (T_ - 1);
        int idx = (b * H_ + h) * T_ + t;
        float c = cosf(v), s = sinf(v);
        if (isK) { ck[idx] = c; sk[idx] = s; }
        else     { cq[idx] = c; sq[idx] = s; }
    }
}

// ---------------- K2: V projection GEMM ----------------
// C[m, h*64+e] = sum_k A[m,k] * WV[h,k,e]; written as Vt[b,h,t,e]
__global__ __launch_bounds__(256) void gemm_v(const float* __restrict__ A,
                                              const float* __restrict__ WV,
                                              float* __restrict__ Vt) {
    __shared__ float As[16][65];
    __shared__ float Bs[16][64];
    int m0 = blockIdx.x * 64;
    int h  = blockIdx.y;             // BN==Dh==64 -> one head per block column
    int tid = threadIdx.x;
    int ty = tid >> 4, tx = tid & 15;
    int arow = tid >> 2, ac4 = (tid & 3) * 4;
    int brow = tid >> 4, be4 = (tid & 15) * 4;
    float acc[4][4] = {};
    for (int k0 = 0; k0 < D_; k0 += 16) {
        float4 av = *(const float4*)(A + (size_t)(m0 + arow) * D_ + k0 + ac4);
        float4 bv = *(const float4*)(WV + (size_t)h * D_ * DH_ + (size_t)(k0 + brow) * DH_ + be4);
        __syncthreads();
        As[ac4 + 0][arow] = av.x; As[ac4 + 1][arow] = av.y;
        As[ac4 + 2][arow] = av.z; As[ac4 + 3][arow] = av.w;
        *(float4*)&Bs[brow][be4] = bv;
        __syncthreads();
#pragma unroll
        for (int kk = 0; kk < 16; ++kk) {
            float a[4], b[4];
#pragma unroll
            for (int ii = 0; ii < 4; ++ii) a[ii] = As[kk][ty + 16 * ii];
#pragma unroll
            for (int jj = 0; jj < 4; ++jj) b[jj] = Bs[kk][tx + 16 * jj];
#pragma unroll
            for (int ii = 0; ii < 4; ++ii)
#pragma unroll
                for (int jj = 0; jj < 4; ++jj)
                    acc[ii][jj] = fmaf(a[ii], b[jj], acc[ii][jj]);
        }
    }
#pragma unroll
    for (int ii = 0; ii < 4; ++ii) {
        int m = m0 + ty + 16 * ii;
        int b = m >> 12, t = m & (T_ - 1);
        float* dst = Vt + (((size_t)(b * H_ + h) * T_ + t) << 6);
#pragma unroll
        for (int jj = 0; jj < 4; ++jj) dst[tx + 16 * jj] = acc[ii][jj];
    }
}

// ---------------- K3: per-chunk sums of ck*V, sk*V (and scalar ck, sk) ----------------
__global__ __launch_bounds__(64) void chunk_sums(const float* __restrict__ Vt,
                                                 const float* __restrict__ ck,
                                                 const float* __restrict__ sk,
                                                 float* __restrict__ csC, float* __restrict__ csS,
                                                 float* __restrict__ kcC, float* __restrict__ kcS) {
    int blk = blockIdx.x;
    int c = blk & (NC_ - 1);
    int bh = blk >> 6;               // b*H + h
    int e = threadIdx.x;
    const float* vbase = Vt + (((size_t)bh * T_) << 6);
    const float* ckb = ck + (size_t)bh * T_;
    const float* skb = sk + (size_t)bh * T_;
    float sc = 0.f, ss = 0.f, kc = 0.f, ks = 0.f;
    for (int i = 0; i < CS_; ++i) {
        int t = c * CS_ + i;
        float cv = ckb[t], sv = skb[t];
        float v = vbase[((size_t)t << 6) + e];
        sc = fmaf(cv, v, sc); ss = fmaf(sv, v, ss);
        kc += cv; ks += sv;
    }
    size_t oidx = ((size_t)bh * NC_ + c) * 64 + e;
    csC[oidx] = sc; csS[oidx] = ss;
    if (e == 0) { kcC[bh * NC_ + c] = kc; kcS[bh * NC_ + c] = ks; }
}

// ---------------- K4: exclusive scan of chunk sums (per b,h) ----------------
__global__ __launch_bounds__(64) void scan_chunks(float* __restrict__ csC, float* __restrict__ csS,
                                                  float* __restrict__ kcC, float* __restrict__ kcS) {
    int bh = blockIdx.x;
    int e = threadIdx.x;
    float rc = 0.f, rs = 0.f, rkc = 0.f, rks = 0.f;
    for (int c = 0; c < NC_; ++c) {
        size_t idx = ((size_t)bh * NC_ + c) * 64 + e;
        float tc = csC[idx]; csC[idx] = rc; rc += tc;
        float ts = csS[idx]; csS[idx] = rs; rs += ts;
        if (e == 0) {
            int i2 = bh * NC_ + c;
            float a = kcC[i2]; kcC[i2] = rkc; rkc += a;
            float b2 = kcS[i2]; kcS[i2] = rks; rks += b2;
        }
    }
}

// ---------------- K5: finalize — local cumsum + offsets, normalize, write heads ----------------
// heads layout: [m, h*64+e] row-major (for the output GEMM)
__global__ __launch_bounds__(64) void finalize(const float* __restrict__ Vt,
                                               const float* __restrict__ cq, const float* __restrict__ sq,
                                               const float* __restrict__ ck, const float* __restrict__ sk,
                                               const float* __restrict__ csC, const float* __restrict__ csS,
                                               const float* __restrict__ kcC, const float* __restrict__ kcS,
                                               float* __restrict__ heads) {
    int blk = blockIdx.x;
    int c = blk & (NC_ - 1);
    int bh = blk >> 6;
    int b = bh >> 4, h = bh & 15;
    int e = threadIdx.x;
    size_t cidx = ((size_t)bh * NC_ + c) * 64 + e;
    float offc = csC[cidx], offs = csS[cidx];
    float koffc = kcC[bh * NC_ + c], koffs = kcS[bh * NC_ + c];
    const float* vbase = Vt + (((size_t)bh * T_) << 6);
    int sbase = bh * T_;
    float rc = 0.f, rs = 0.f, rkc = 0.f, rks = 0.f;
    for (int i = 0; i < CS_; ++i) {
        int t = c * CS_ + i;
        float cv = ck[sbase + t], sv = sk[sbase + t];
        float v = vbase[((size_t)t << 6) + e];
        rc = fmaf(cv, v, rc); rs = fmaf(sv, v, rs);
        rkc += cv; rks += sv;
        float cqv = cq[sbase + t], sqv = sq[sbase + t];
        float num = cqv * (offc + rc) + sqv * (offs + rs);
        float den = cqv * (koffc + rkc) + sqv * (koffs + rks) + EPS_;
        heads[(size_t)(b * T_ + t) * HD_ + h * DH_ + e] = num / den;
    }
}

// ---------------- K6: output GEMM: Out[m,d] = sum_he heads[m,he] * Wo2[he,d] ----------------
__global__ __launch_bounds__(256) void gemm_o(const float* __restrict__ A,
                                              const float* __restrict__ Wo2,
                                              float* __restrict__ Out) {
    __shared__ float As[16][65];
    __shared__ float Bs[16][64];
    int m0 = blockIdx.x * 64;
    int n0 = blockIdx.y * 64;
    int tid = threadIdx.x;
    int ty = tid >> 4, tx = tid & 15;
    int arow = tid >> 2, ac4 = (tid & 3) * 4;
    int brow = tid >> 4, be4 = (tid & 15) * 4;
    float acc[4][4] = {};
    for (int k0 = 0; k0 < HD_; k0 += 16) {
        float4 av = *(const float4*)(A + (size_t)(m0 + arow) * HD_ + k0 + ac4);
        float4 bv = *(const float4*)(Wo2 + (size_t)(k0 + brow) * D_ + n0 + be4);
        __syncthreads();
        As[ac4 + 0][arow] = av.x; As[ac4 + 1][arow] = av.y;
        As[ac4 + 2][arow] = av.z; As[ac4 + 3][arow] = av.w;
        *(float4*)&Bs[brow][be4] = bv;
        __syncthreads();
#pragma unroll
        for (int kk = 0; kk < 16; ++kk) {
            float a[4], b[4];
#pragma unroll
            for (int ii = 0; ii < 4; ++ii) a[ii] = As[kk][ty + 16 * ii];
#pragma unroll
            for (int jj = 0; jj < 4; ++jj) b[jj] = Bs[kk][tx + 16 * jj];
#pragma unroll
            for (int ii = 0; ii < 4; ++ii)
#pragma unroll
                for (int jj = 0; jj < 4; ++jj)
                    acc[ii][jj] = fmaf(a[ii], b[jj], acc[ii][jj]);
        }
    }
#pragma unroll
    for (int ii = 0; ii < 4; ++ii) {
        int m = m0 + ty + 16 * ii;
        float* dst = Out + (size_t)m * D_ + n0;
#pragma unroll
        for (int jj = 0; jj < 4; ++jj) dst[tx + 16 * jj] = acc[ii][jj];
    }
}

extern "C" void kernel_launch(void* const* d_in, const int* in_sizes, int n_in,
                              void* d_out, int out_size, void* d_ws, size_t ws_size,
                              hipStream_t stream) {
    const float* query = (const float*)d_in[0];
    const float* W_Q   = (const float*)d_in[1];
    const float* W_K   = (const float*)d_in[2];
    const float* W_V   = (const float*)d_in[3];
    const float* W_O   = (const float*)d_in[4];
    float* out = (float*)d_out;

    float* ws = (float*)d_ws;
    size_t off = 0;
    float* cq    = ws + off; off += (size_t)B_ * H_ * T_;        // 262144
    float* sq    = ws + off; off += (size_t)B_ * H_ * T_;
    float* ck    = ws + off; off += (size_t)B_ * H_ * T_;
    float* sk    = ws + off; off += (size_t)B_ * H_ * T_;
    float* Vt    = ws + off; off += (size_t)M_ * HD_;            // 16777216
    float* heads = ws + off; off += (size_t)M_ * HD_;            // 16777216
    float* Wo2   = ws + off; off += (size_t)HD_ * D_;            // 1048576
    float* csC   = ws + off; off += (size_t)B_ * H_ * NC_ * DH_; // 262144
    float* csS   = ws + off; off += (size_t)B_ * H_ * NC_ * DH_;
    float* kcC   = ws + off; off += (size_t)B_ * H_ * NC_;       // 4096
    float* kcS   = ws + off; off += (size_t)B_ * H_ * NC_;

    transpose_wo<<<dim3((D_ * HD_) / 256), 256, 0, stream>>>(W_O, Wo2);
    qk_proj<<<dim3(M_), 256, 0, stream>>>(query, W_Q, W_K, cq, sq, ck, sk);
    gemm_v<<<dim3(M_ / 64, HD_ / 64), 256, 0, stream>>>(query, W_V, Vt);
    chunk_sums<<<dim3(B_ * H_ * NC_), 64, 0, stream>>>(Vt, ck, sk, csC, csS, kcC, kcS);
    scan_chunks<<<dim3(B_ * H_), 64, 0, stream>>>(csC, csS, kcC, kcS);
    finalize<<<dim3(B_ * H_ * NC_), 64, 0, stream>>>(Vt, cq, sq, ck, sk, csC, csS, kcC, kcS, heads);
    gemm_o<<<dim3(M_ / 64, D_ / 64), 256, 0, stream>>>(heads, Wo2, out);
}

// Round 4
// 425.872 us; speedup vs baseline: 3.2401x; 3.2401x over previous
//
#include <hip/hip_runtime.h>
#include <math.h>

#define B_ 4
#define T_ 4096
#define D_ 1024
#define H_ 16
#define DH_ 64
#define M_ (B_*T_)      // 16384
#define HD_ (H_*DH_)    // 1024
#define NC_ 64
#define CS_ 64
#define PI_4 0.78539816339744830962f
#define EPS_ 1e-6f

typedef short bf16x8 __attribute__((ext_vector_type(8)));
typedef float f32x4 __attribute__((ext_vector_type(4)));

// round-to-nearest-even f32 -> bf16, no header dependency
static __device__ __forceinline__ unsigned short f2bf(float f) {
    unsigned u = __builtin_bit_cast(unsigned, f);
    unsigned rounding = 0x7fffu + ((u >> 16) & 1u);
    return (unsigned short)((u + rounding) >> 16);
}

#define GLDS16(gsrc, ldst) \
    __builtin_amdgcn_global_load_lds((const __attribute__((address_space(1))) void*)(gsrc), \
                                     (__attribute__((address_space(3))) void*)(ldst), 16, 0, 0)

// ---------------- converts ----------------
__global__ __launch_bounds__(256) void conv_a(const float* __restrict__ in,
                                              unsigned short* __restrict__ out) {
    int i = blockIdx.x * 256 + threadIdx.x;          // over 4M float4s
    float4 v = ((const float4*)in)[i];
    ushort4 o;
    o.x = f2bf(v.x); o.y = f2bf(v.y); o.z = f2bf(v.z); o.w = f2bf(v.w);
    ((ushort4*)out)[i] = o;
}

// Wv_bt[(h*64+e)*1024 + k] = WV[h*65536 + k*64 + e]
__global__ __launch_bounds__(256) void conv_wv(const float* __restrict__ WV,
                                               unsigned short* __restrict__ Bt) {
    int f = blockIdx.x * 256 + threadIdx.x;          // 1M
    int n = f >> 10, k = f & 1023;
    int h = n >> 6, e = n & 63;
    Bt[f] = f2bf(WV[h * 65536 + k * 64 + e]);
}

// Wo_bt[d*1024 + h*64 + e] = WO[d*1024 + e*16 + h]
__global__ __launch_bounds__(256) void conv_wo(const float* __restrict__ WO,
                                               unsigned short* __restrict__ Bt) {
    int f = blockIdx.x * 256 + threadIdx.x;          // 1M
    int d = f >> 10, rem = f & 1023;
    int h = rem >> 6, e = rem & 63;
    Bt[f] = f2bf(WO[d * 1024 + e * 16 + h]);
}

// ---------------- qk projections + tanh + cos/sin ----------------
__global__ __launch_bounds__(256) void qk_proj(const float* __restrict__ q,
                                               const float* __restrict__ wq,
                                               const float* __restrict__ wk,
                                               float* __restrict__ cq, float* __restrict__ sq,
                                               float* __restrict__ ck, float* __restrict__ sk) {
    __shared__ float row[D_];
    int m = blockIdx.x;
    int tid = threadIdx.x;
    const float4* src = (const float4*)(q + (size_t)m * D_);
    ((float4*)row)[tid] = src[tid];
    __syncthreads();
    int out = tid >> 3;
    int sub = tid & 7;
    int h = out >> 1;
    int isK = out & 1;
    const float* w = (isK ? wk : wq) + (size_t)h * D_;
    float acc = 0.f;
#pragma unroll 8
    for (int i = 0; i < 128; ++i) {
        int d = sub + (i << 3);
        acc = fmaf(row[d], w[d], acc);
    }
    acc += __shfl_xor(acc, 1);
    acc += __shfl_xor(acc, 2);
    acc += __shfl_xor(acc, 4);
    if (sub == 0) {
        float v = tanhf(acc) * PI_4;
        int b = m >> 12, t = m & (T_ - 1);
        int idx = (b * H_ + h) * T_ + t;
        float c = cosf(v), s = sinf(v);
        if (isK) { ck[idx] = c; sk[idx] = s; }
        else     { cq[idx] = c; sq[idx] = s; }
    }
}

// ---------------- bf16 MFMA GEMM core (m97 structure) ----------------
// C = A[M,K=1024] x B (Bt[n][k] transposed layout), 128x128 tile, BK=32.
// OUT_MODE 0: store to Vt[b,h,t,e]; OUT_MODE 1: store to Out[m*1024+n].
template <int OUT_MODE>
__global__ __launch_bounds__(256) void gemm_bf16(const unsigned short* __restrict__ A,
                                                 const unsigned short* __restrict__ Bt,
                                                 float* __restrict__ Out) {
    __shared__ short As[128 * 32];
    __shared__ short Bs[128 * 32];
    const int K = 1024;
    int tid = threadIdx.x;
    int m0 = blockIdx.x * 128;
    int n0 = blockIdx.y * 128;
    int lane = tid & 63, w = tid >> 6;
    int wm = (w >> 1) * 64, wn = (w & 1) * 64;
    int r = lane & 15, g = lane >> 4;

    int srow = tid >> 2;            // 0..63 staged row within a round
    int skq  = (tid & 3) * 8;       // k offset (8 bf16 = 16B)

    f32x4 acc[4][4];
#pragma unroll
    for (int i = 0; i < 4; ++i)
#pragma unroll
        for (int j = 0; j < 4; ++j) acc[i][j] = (f32x4)0.f;

    const unsigned short* gA = A  + (size_t)(m0 + srow) * K + skq;
    const unsigned short* gB = Bt + (size_t)(n0 + srow) * K + skq;
    char* lA = (char*)As + tid * 16;
    char* lB = (char*)Bs + tid * 16;

    for (int k0 = 0; k0 < K; k0 += 32) {
        // stage A,B tiles (128x32 bf16 each): 2 rounds of 64 rows each
        GLDS16(gA + k0,            lA);
        GLDS16(gA + k0 + 64 * K,   lA + 4096);
        GLDS16(gB + k0,            lB);
        GLDS16(gB + k0 + 64 * K,   lB + 4096);
        __syncthreads();            // drains vmcnt+lgkm (compiler-emitted)

        bf16x8 af[4], bf[4];
#pragma unroll
        for (int i = 0; i < 4; ++i)
            af[i] = *(const bf16x8*)&As[(wm + i * 16 + r) * 32 + g * 8];
#pragma unroll
        for (int j = 0; j < 4; ++j)
            bf[j] = *(const bf16x8*)&Bs[(wn + j * 16 + r) * 32 + g * 8];
#pragma unroll
        for (int i = 0; i < 4; ++i)
#pragma unroll
            for (int j = 0; j < 4; ++j)
                acc[i][j] = __builtin_amdgcn_mfma_f32_16x16x32_bf16(af[i], bf[j], acc[i][j], 0, 0, 0);
        __syncthreads();            // protect LDS before next stage
    }

#pragma unroll
    for (int i = 0; i < 4; ++i) {
#pragma unroll
        for (int j = 0; j < 4; ++j) {
#pragma unroll
            for (int q = 0; q < 4; ++q) {
                int m = m0 + wm + i * 16 + g * 4 + q;
                int n = n0 + wn + j * 16 + r;
                if (OUT_MODE == 0) {
                    int b = m >> 12, t = m & (T_ - 1);
                    int h = n >> 6, e = n & 63;
                    Out[(((size_t)(b * H_ + h) * T_ + t) << 6) + e] = acc[i][j][q];
                } else {
                    Out[(size_t)m * D_ + n] = acc[i][j][q];
                }
            }
        }
    }
}

// ---------------- chunk sums ----------------
__global__ __launch_bounds__(64) void chunk_sums(const float* __restrict__ Vt,
                                                 const float* __restrict__ ck,
                                                 const float* __restrict__ sk,
                                                 float* __restrict__ csC, float* __restrict__ csS,
                                                 float* __restrict__ kcC, float* __restrict__ kcS) {
    int blk = blockIdx.x;
    int c = blk & (NC_ - 1);
    int bh = blk >> 6;
    int e = threadIdx.x;
    const float* vbase = Vt + (((size_t)bh * T_) << 6);
    const float* ckb = ck + (size_t)bh * T_;
    const float* skb = sk + (size_t)bh * T_;
    float sc = 0.f, ss = 0.f, kc = 0.f, ks = 0.f;
    for (int i = 0; i < CS_; ++i) {
        int t = c * CS_ + i;
        float cv = ckb[t], sv = skb[t];
        float v = vbase[((size_t)t << 6) + e];
        sc = fmaf(cv, v, sc); ss = fmaf(sv, v, ss);
        kc += cv; ks += sv;
    }
    size_t oidx = ((size_t)bh * NC_ + c) * 64 + e;
    csC[oidx] = sc; csS[oidx] = ss;
    if (e == 0) { kcC[bh * NC_ + c] = kc; kcS[bh * NC_ + c] = ks; }
}

// ---------------- exclusive scan over chunks ----------------
__global__ __launch_bounds__(64) void scan_chunks(float* __restrict__ csC, float* __restrict__ csS,
                                                  float* __restrict__ kcC, float* __restrict__ kcS) {
    int bh = blockIdx.x;
    int e = threadIdx.x;
    float rc = 0.f, rs = 0.f, rkc = 0.f, rks = 0.f;
    for (int c = 0; c < NC_; ++c) {
        size_t idx = ((size_t)bh * NC_ + c) * 64 + e;
        float tc = csC[idx]; csC[idx] = rc; rc += tc;
        float ts = csS[idx]; csS[idx] = rs; rs += ts;
        if (e == 0) {
            int i2 = bh * NC_ + c;
            float a = kcC[i2]; kcC[i2] = rkc; rkc += a;
            float b2 = kcS[i2]; kcS[i2] = rks; rks += b2;
        }
    }
}

// ---------------- finalize: local cumsum, normalize, bf16 heads ----------------
__global__ __launch_bounds__(64) void finalize(const float* __restrict__ Vt,
                                               const float* __restrict__ cq, const float* __restrict__ sq,
                                               const float* __restrict__ ck, const float* __restrict__ sk,
                                               const float* __restrict__ csC, const float* __restrict__ csS,
                                               const float* __restrict__ kcC, const float* __restrict__ kcS,
                                               unsigned short* __restrict__ heads) {
    int blk = blockIdx.x;
    int c = blk & (NC_ - 1);
    int bh = blk >> 6;
    int b = bh >> 4, h = bh & 15;
    int e = threadIdx.x;
    size_t cidx = ((size_t)bh * NC_ + c) * 64 + e;
    float offc = csC[cidx], offs = csS[cidx];
    float koffc = kcC[bh * NC_ + c], koffs = kcS[bh * NC_ + c];
    const float* vbase = Vt + (((size_t)bh * T_) << 6);
    int sbase = bh * T_;
    float rc = 0.f, rs = 0.f, rkc = 0.f, rks = 0.f;
    for (int i = 0; i < CS_; ++i) {
        int t = c * CS_ + i;
        float cv = ck[sbase + t], sv = sk[sbase + t];
        float v = vbase[((size_t)t << 6) + e];
        rc = fmaf(cv, v, rc); rs = fmaf(sv, v, rs);
        rkc += cv; rks += sv;
        float cqv = cq[sbase + t], sqv = sq[sbase + t];
        float num = cqv * (offc + rc) + sqv * (offs + rs);
        float den = cqv * (koffc + rkc) + sqv * (koffs + rks) + EPS_;
        heads[(size_t)(b * T_ + t) * HD_ + h * DH_ + e] = f2bf(num / den);
    }
}

extern "C" void kernel_launch(void* const* d_in, const int* in_sizes, int n_in,
                              void* d_out, int out_size, void* d_ws, size_t ws_size,
                              hipStream_t stream) {
    const float* query = (const float*)d_in[0];
    const float* W_Q   = (const float*)d_in[1];
    const float* W_K   = (const float*)d_in[2];
    const float* W_V   = (const float*)d_in[3];
    const float* W_O   = (const float*)d_in[4];
    float* out = (float*)d_out;

    float* ws = (float*)d_ws;
    size_t off = 0;
    float* cq  = ws + off; off += (size_t)B_ * H_ * T_;          // 262144
    float* sq  = ws + off; off += (size_t)B_ * H_ * T_;
    float* ck  = ws + off; off += (size_t)B_ * H_ * T_;
    float* sk  = ws + off; off += (size_t)B_ * H_ * T_;
    float* Vt  = ws + off; off += (size_t)M_ * HD_;              // 16777216 f32
    float* csC = ws + off; off += (size_t)B_ * H_ * NC_ * DH_;
    float* csS = ws + off; off += (size_t)B_ * H_ * NC_ * DH_;
    float* kcC = ws + off; off += (size_t)B_ * H_ * NC_;
    float* kcS = ws + off; off += (size_t)B_ * H_ * NC_;
    unsigned short* us = (unsigned short*)(ws + off);
    size_t uoff = 0;
    unsigned short* Aq       = us + uoff; uoff += (size_t)M_ * D_;   // 16M bf16
    unsigned short* heads_bf = us + uoff; uoff += (size_t)M_ * HD_;  // 16M bf16
    unsigned short* Wv_bt    = us + uoff; uoff += (size_t)HD_ * D_;  // 1M bf16
    unsigned short* Wo_bt    = us + uoff; uoff += (size_t)D_ * HD_;  // 1M bf16

    conv_a<<<dim3(M_ * D_ / 1024), 256, 0, stream>>>(query, Aq);
    conv_wv<<<dim3(HD_ * D_ / 256), 256, 0, stream>>>(W_V, Wv_bt);
    conv_wo<<<dim3(D_ * HD_ / 256), 256, 0, stream>>>(W_O, Wo_bt);
    qk_proj<<<dim3(M_), 256, 0, stream>>>(query, W_Q, W_K, cq, sq, ck, sk);
    gemm_bf16<0><<<dim3(M_ / 128, HD_ / 128), 256, 0, stream>>>(Aq, Wv_bt, Vt);
    chunk_sums<<<dim3(B_ * H_ * NC_), 64, 0, stream>>>(Vt, ck, sk, csC, csS, kcC, kcS);
    scan_chunks<<<dim3(B_ * H_), 64, 0, stream>>>(csC, csS, kcC, kcS);
    finalize<<<dim3(B_ * H_ * NC_), 64, 0, stream>>>(Vt, cq, sq, ck, sk, csC, csS, kcC, kcS, heads_bf);
    gemm_bf16<1><<<dim3(M_ / 128, D_ / 128), 256, 0, stream>>>(heads_bf, Wo_bt, out);
}